// Round 7
// baseline (932.036 us; speedup 1.0000x reference)
//
#include <hip/hip_runtime.h>

// ---------------------------------------------------------------------------
// TransNetSweepingExplRhs — analytic reduction (derivation in R1/R2):
//   h = x@W_in^T + b_in ; th = tanh(h); r1u = h + 0.1 b1
//   Q_i = I/11 - (0.01/121) W_i^T W_i      (1-term Neumann inverse)
//   b1v = 11 th + 0.1 (r1u@W1); y1v = b1v@Q1
//   r2u = r1u - 0.1 (y1v@W1^T) + 0.1 b2
//   b2v = 10 th + y1v + 0.1 (r2u@W2); y2v = b2v@Q2
//   y2u = r2u - 0.1 (y2v@W2^T);  out = softmax(y2u@W_out^T + b_out)
// R7: ONE persistent kernel (256 blocks x 512 thr = 1 block/CU guaranteed
// co-resident; 8 waves = 2/SIMD, same as R6) with agent-scope spin-barrier
// grid sync (finite spin -> deadlock shows as absmax fail, not a hang).
// Kills ~35us of inter-dispatch gaps. K-loop = R6's proven 3-buffer
// counted-vmcnt pipeline, tile 64x128 (every stage = exactly 256 tiles).
// All inter-stage buffers write-once/read-once; __threadfence both sides
// of each barrier for cross-XCD L2 coherence (G16).
// ---------------------------------------------------------------------------

typedef short bf16x8 __attribute__((ext_vector_type(8)));
typedef float f32x4 __attribute__((ext_vector_type(4)));

#define M1 1048576
#define NB 256

__device__ __forceinline__ unsigned short f2b(float f) {
  union { float f; unsigned int u; } v; v.f = f;
  unsigned int u = v.u;
  return (unsigned short)((u + 0x7FFFu + ((u >> 16) & 1u)) >> 16);
}

__device__ __forceinline__ void gload16(const void* g, void* l) {
  __builtin_amdgcn_global_load_lds(
      (const __attribute__((address_space(1))) unsigned int*)g,
      (__attribute__((address_space(3))) unsigned int*)l, 16, 0, 0);
}

struct KP {
  const float *x, *W_in, *b_in, *W1, *b1, *W2, *b2, *W_out, *b_out;
  float* out;
  unsigned short *xb, *winb, *wb, *wtb, *qb, *woutb;
  unsigned short *zb0, *zb1, *zb2, *zb3, *zb4, *zb5, *zb6;
  float *boutp, *r1u, *th, *y1v, *r2u, *lgts;
  unsigned* bar;
};

// grid barrier: arrive + acquire-spin, device-scope fences both sides.
// Finite spin: on deadlock we exit (wrong result) instead of hanging.
__device__ __forceinline__ void gbar(unsigned* cnt, int slot) {
  __syncthreads();
  __threadfence();  // release: our global writes visible agent-wide
  if (threadIdx.x == 0) {
    __hip_atomic_fetch_add(cnt + slot, 1u, __ATOMIC_ACQ_REL,
                           __HIP_MEMORY_SCOPE_AGENT);
    for (int it = 0; it < 8000000; ++it) {
      unsigned v = __hip_atomic_load(cnt + slot, __ATOMIC_ACQUIRE,
                                     __HIP_MEMORY_SCOPE_AGENT);
      if (v >= NB) break;
      __builtin_amdgcn_s_sleep(2);
    }
  }
  __syncthreads();
  __threadfence();  // acquire: invalidate L1 so we see remote writes
}

// C[m,n] = sum_k A[m,k]*B[n,k], K=1024, tile 64(M)x128(N) at (bx,by), BK=64.
// 8 waves (2x4), wave tile 32x32. 3-buffer depth-2 pipeline, counted vmcnt.
// Rotation swizzle: chunk c of row r lives at LDS slot (c+r)&7 (both sides).
template <int MODE>
__device__ __forceinline__ void gemm_tile(
    const unsigned short* __restrict__ A, const unsigned short* __restrict__ B,
    int bx, int by,
    const float* bias0, const float* bias1,
    const float* src0, const float* src1,
    float* dstf0, float* dstf1, unsigned short* dstbf,
    short (*As)[4096], short (*Bs)[8192]) {
  const int tid = threadIdx.x;
  const int lane = tid & 63;
  const int wid = tid >> 6;   // 0..7
  const int wr = wid >> 2;    // 0..1  (32-row halves)
  const int wc = wid & 3;     // 0..3  (32-col quarters)
  const int m0 = bx * 64;
  const int n0 = by * 128;
  const int l15 = lane & 15;
  const int kb = lane >> 4;

  const int sr = tid >> 3;                  // 0..63
  const int sg = ((tid & 7) - sr) & 7;      // pre-swizzled source chunk
  const unsigned short* Asrc = A + (size_t)(m0 + sr) * 1024 + sg * 8;
  const unsigned short* Bsrc = B + (size_t)(n0 + sr) * 1024 + sg * 8;
  const unsigned short* Bsrc2 = Bsrc + (size_t)64 * 1024;
  const int o = tid * 8;

  f32x4 acc[2][2];
#pragma unroll
  for (int f = 0; f < 2; ++f)
#pragma unroll
    for (int g = 0; g < 2; ++g) acc[f][g] = (f32x4){0.f, 0.f, 0.f, 0.f};

#define STG(kt, buf)                                \
  do {                                              \
    gload16(Asrc + (kt) * 64, &As[(buf)][o]);       \
    gload16(Bsrc + (kt) * 64, &Bs[(buf)][o]);       \
    gload16(Bsrc2 + (kt) * 64, &Bs[(buf)][4096 + o]); \
  } while (0)

  STG(0, 0);
  STG(1, 1);

#pragma unroll
  for (int t = 0; t < 16; ++t) {
    if (t < 15) {
      asm volatile("s_waitcnt vmcnt(3)" ::: "memory");
    } else {
      asm volatile("s_waitcnt vmcnt(0)" ::: "memory");
    }
    __builtin_amdgcn_sched_barrier(0);
    __builtin_amdgcn_s_barrier();
    __builtin_amdgcn_sched_barrier(0);
    if (t + 2 < 16) STG(t + 2, (t + 2) % 3);
    const int cb = t % 3;
    bf16x8 av[2][2], bv[2][2];
#pragma unroll
    for (int f = 0; f < 2; ++f) {
      const int ra = wr * 32 + f * 16 + l15;
#pragma unroll
      for (int ks = 0; ks < 2; ++ks) {
        const int qa = (ks * 4 + kb + ra) & 7;
        av[f][ks] = *reinterpret_cast<const bf16x8*>(&As[cb][ra * 64 + qa * 8]);
      }
    }
#pragma unroll
    for (int g = 0; g < 2; ++g) {
      const int rb = wc * 32 + g * 16 + l15;
#pragma unroll
      for (int ks = 0; ks < 2; ++ks) {
        const int qn = (ks * 4 + kb + rb) & 7;
        bv[g][ks] = *reinterpret_cast<const bf16x8*>(&Bs[cb][rb * 64 + qn * 8]);
      }
    }
#pragma unroll
    for (int ks = 0; ks < 2; ++ks)
#pragma unroll
      for (int f = 0; f < 2; ++f)
#pragma unroll
        for (int g = 0; g < 2; ++g)
          acc[f][g] = __builtin_amdgcn_mfma_f32_16x16x32_bf16(av[f][ks], bv[g][ks], acc[f][g], 0, 0, 0);
  }
#undef STG

  // epilogue: C/D layout col = lane&15, row = (lane>>4)*4 + j
#pragma unroll
  for (int f = 0; f < 2; ++f) {
#pragma unroll
    for (int g = 0; g < 2; ++g) {
#pragma unroll
      for (int j = 0; j < 4; ++j) {
        int m = m0 + wr * 32 + f * 16 + kb * 4 + j;
        int n = n0 + wc * 32 + g * 16 + l15;
        size_t idx = (size_t)m * 1024 + n;
        float v = acc[f][g][j];
        if (MODE == 0) {                  // raw bf16
          dstbf[idx] = f2b(v);
        } else if (MODE == 1) {           // h-stage
          float h = v + bias0[n];
          float thv = tanhf(h);
          float r = h + 0.1f * bias1[n];
          dstf0[idx] = r;
          dstf1[idx] = thv;
          dstbf[idx] = f2b(r);
        } else if (MODE == 2) {           // b1v = 11 th + 0.1 c1
          dstbf[idx] = f2b(11.0f * src0[idx] + 0.1f * v);
        } else if (MODE == 3) {           // y1v
          dstf0[idx] = v;
          dstbf[idx] = f2b(v);
        } else if (MODE == 4) {           // r2u = r1u - 0.1 d1 + 0.1 b2
          float r = src0[idx] - 0.1f * v + 0.1f * bias0[n];
          dstf0[idx] = r;
          dstbf[idx] = f2b(r);
        } else if (MODE == 5) {           // b2v = 10 th + y1v + 0.1 c2
          dstbf[idx] = f2b(10.0f * src0[idx] + src1[idx] + 0.1f * v);
        } else if (MODE == 7) {           // y2u = r2u - 0.1 d2
          dstbf[idx] = f2b(src0[idx] - 0.1f * v);
        } else if (MODE == 8) {           // logits
          dstf0[idx] = v + bias0[n];
        } else {                          // MODE 9: Q = I/11 - (0.01/121) P
          float q = (m == n ? (1.0f / 11.0f) : 0.0f) - (0.01f / 121.0f) * v;
          dstbf[idx] = f2b(q);
        }
      }
    }
  }
}

__global__ __launch_bounds__(512) void fused(KP p) {
  __shared__ short As[3][4096];
  __shared__ short Bs[3][8192];
  const int b = blockIdx.x;
  const int tid = threadIdx.x;
  const int lane = tid & 63;
  const int wid = tid >> 6;

  // XCD-sharded map for the 32x8 grid of 64x128 tiles (chain + G0)
  const int bx = ((b & 7) << 2) | ((b >> 3) & 3);
  const int by = b >> 5;

  // ---------------- S0: prep slices ----------------
  {
    // (a) W1/W2 transpose+convert: 8 of 2048 32x32-tile jobs
    float(*ft)[33] = reinterpret_cast<float(*)[33]>(&Bs[0][0]);
    const int tx = tid & 31;
    const int ty = tid >> 5;  // 0..15
#pragma unroll
    for (int i2 = 0; i2 < 8; ++i2) {
      int t = b * 8 + i2;
      const float* W = (t & 1024) ? p.W2 : p.W1;
      unsigned short* Wb = p.wb + ((size_t)(t >> 10) << 20);
      unsigned short* WTb = p.wtb + ((size_t)(t >> 10) << 20);
      int rem = t & 1023;
      int tbx = rem & 31, tby = rem >> 5;
      __syncthreads();
#pragma unroll
      for (int i = ty; i < 32; i += 16) {
        float v = W[(size_t)(tby * 32 + i) * 1024 + tbx * 32 + tx];
        ft[i][tx] = v;
        Wb[(size_t)(tby * 32 + i) * 1024 + tbx * 32 + tx] = f2b(v);
      }
      __syncthreads();
#pragma unroll
      for (int i = ty; i < 32; i += 16)
        WTb[(size_t)(tbx * 32 + i) * 1024 + tby * 32 + tx] = f2b(ft[tx][i]);
    }
    // (b) x convert: 4 float4 per thread
    const float4* x4 = (const float4*)p.x;
    ushort4* xb4 = (ushort4*)p.xb;
#pragma unroll
    for (int j = 0; j < 4; ++j) {
      int i = b * 2048 + j * 512 + tid;
      float4 v = x4[i];
      xb4[i] = (ushort4){f2b(v.x), f2b(v.y), f2b(v.z), f2b(v.w)};
    }
    // (c) W_in convert
    const float4* wi4 = (const float4*)p.W_in;
    ushort4* wib4 = (ushort4*)p.winb;
#pragma unroll
    for (int j = 0; j < 2; ++j) {
      int i = b * 1024 + j * 512 + tid;
      float4 v = wi4[i];
      wib4[i] = (ushort4){f2b(v.x), f2b(v.y), f2b(v.z), f2b(v.w)};
    }
    // (d) W_out pad
    const float4* wo4 = (const float4*)p.W_out;
    ushort4* wob4 = (ushort4*)p.woutb;
#pragma unroll
    for (int j = 0; j < 2; ++j) {
      int i = b * 1024 + j * 512 + tid;
      ushort4 q = (ushort4){0, 0, 0, 0};
      if ((i >> 8) < 1000) {
        float4 v = wo4[i];
        q = (ushort4){f2b(v.x), f2b(v.y), f2b(v.z), f2b(v.w)};
      }
      wob4[i] = q;
    }
    // (e) b_out pad
    if (b == 0)
      for (int j = tid; j < 1024; j += 512)
        p.boutp[j] = (j < 1000) ? p.b_out[j] : 0.0f;
  }
  gbar(p.bar, 0);

  // ---------------- S1: G0 (h-stage) + QG (Q1,Q2) ----------------
  gemm_tile<1>(p.xb, p.winb, bx, by, p.b_in, p.b1, nullptr, nullptr,
               p.r1u, p.th, p.zb0, As, Bs);
  __syncthreads();
  {
    const int z = b >> 7;
    const int rem = b & 127;
    const int qbx = ((rem & 7) << 1) | ((rem >> 3) & 1);
    const int qby = (rem >> 4) & 7;
    gemm_tile<9>(p.wtb + (size_t)z * M1, p.wtb + (size_t)z * M1, qbx, qby,
                 nullptr, nullptr, nullptr, nullptr, nullptr, nullptr,
                 p.qb + (size_t)z * M1, As, Bs);
  }
  gbar(p.bar, 1);

  // ---------------- chain ----------------
  gemm_tile<2>(p.zb0, p.wtb, bx, by, nullptr, nullptr, p.th, nullptr,
               nullptr, nullptr, p.zb1, As, Bs);
  gbar(p.bar, 2);
  gemm_tile<3>(p.zb1, p.qb, bx, by, nullptr, nullptr, nullptr, nullptr,
               p.y1v, nullptr, p.zb2, As, Bs);
  gbar(p.bar, 3);
  gemm_tile<4>(p.zb2, p.wb, bx, by, p.b2, nullptr, p.r1u, nullptr,
               p.r2u, nullptr, p.zb3, As, Bs);
  gbar(p.bar, 4);
  gemm_tile<5>(p.zb3, p.wtb + M1, bx, by, nullptr, nullptr, p.th, p.y1v,
               nullptr, nullptr, p.zb4, As, Bs);
  gbar(p.bar, 5);
  gemm_tile<0>(p.zb4, p.qb + M1, bx, by, nullptr, nullptr, nullptr, nullptr,
               nullptr, nullptr, p.zb5, As, Bs);
  gbar(p.bar, 6);
  gemm_tile<7>(p.zb5, p.wb + M1, bx, by, nullptr, nullptr, p.r2u, nullptr,
               nullptr, nullptr, p.zb6, As, Bs);
  gbar(p.bar, 7);
  gemm_tile<8>(p.zb6, p.woutb, bx, by, p.boutp, nullptr, nullptr, nullptr,
               p.lgts, nullptr, nullptr, As, Bs);
  gbar(p.bar, 8);

  // ---------------- softmax: 8 rows per block ----------------
  {
    float* red = reinterpret_cast<float*>(&As[0][0]);  // 16 floats
    for (int rr = 0; rr < 8; ++rr) {
      int row = b * 8 + rr;
      const float* prow = p.lgts + (size_t)row * 1024;
      float* qrow = p.out + (size_t)row * 1000;
      float m = -3.0e38f;
      for (int i = tid; i < 1000; i += 512) m = fmaxf(m, prow[i]);
#pragma unroll
      for (int o2 = 32; o2 > 0; o2 >>= 1) m = fmaxf(m, __shfl_xor(m, o2));
      if (lane == 0) red[wid] = m;
      __syncthreads();
      m = red[0];
#pragma unroll
      for (int w2 = 1; w2 < 8; ++w2) m = fmaxf(m, red[w2]);
      float s = 0.0f;
      for (int i = tid; i < 1000; i += 512) {
        float e = __expf(prow[i] - m);
        qrow[i] = e;
        s += e;
      }
#pragma unroll
      for (int o2 = 32; o2 > 0; o2 >>= 1) s += __shfl_xor(s, o2);
      if (lane == 0) red[8 + wid] = s;
      __syncthreads();
      float sum = red[8];
#pragma unroll
      for (int w2 = 1; w2 < 8; ++w2) sum += red[8 + w2];
      float inv = 1.0f / sum;
      for (int i = tid; i < 1000; i += 512) qrow[i] *= inv;
      __syncthreads();
    }
  }
}

extern "C" void kernel_launch(void* const* d_in, const int* in_sizes, int n_in,
                              void* d_out, int out_size, void* d_ws, size_t ws_size,
                              hipStream_t stream) {
  const size_t Bm = 2048, U = 1024;
  char* ws = (char*)d_ws;
  size_t off = 0;
  auto alloc = [&](size_t bytes) -> void* {
    void* pp = ws + off;
    off += (bytes + 255) & ~(size_t)255;
    return pp;
  };

  KP p;
  p.x = (const float*)d_in[0];
  p.W_in = (const float*)d_in[1];
  p.b_in = (const float*)d_in[2];
  p.W1 = (const float*)d_in[3];
  p.b1 = (const float*)d_in[4];
  p.W2 = (const float*)d_in[5];
  p.b2 = (const float*)d_in[6];
  p.W_out = (const float*)d_in[7];
  p.b_out = (const float*)d_in[8];
  p.out = (float*)d_out;

  p.xb = (unsigned short*)alloc(Bm * U * 2);
  p.winb = (unsigned short*)alloc((size_t)M1 * 2);
  p.wb = (unsigned short*)alloc(2 * (size_t)M1 * 2);
  p.wtb = (unsigned short*)alloc(2 * (size_t)M1 * 2);
  p.qb = (unsigned short*)alloc(2 * (size_t)M1 * 2);
  p.woutb = (unsigned short*)alloc((size_t)M1 * 2);
  p.zb0 = (unsigned short*)alloc(Bm * U * 2);
  p.zb1 = (unsigned short*)alloc(Bm * U * 2);
  p.zb2 = (unsigned short*)alloc(Bm * U * 2);
  p.zb3 = (unsigned short*)alloc(Bm * U * 2);
  p.zb4 = (unsigned short*)alloc(Bm * U * 2);
  p.zb5 = (unsigned short*)alloc(Bm * U * 2);
  p.zb6 = (unsigned short*)alloc(Bm * U * 2);
  p.boutp = (float*)alloc(U * 4);
  p.r1u = (float*)alloc(Bm * U * 4);
  p.th = (float*)alloc(Bm * U * 4);
  p.y1v = (float*)alloc(Bm * U * 4);
  p.r2u = (float*)alloc(Bm * U * 4);
  p.lgts = (float*)alloc(Bm * U * 4);
  p.bar = (unsigned*)alloc(256);

  hipMemsetAsync(p.bar, 0, 256, stream);
  fused<<<NB, 512, 0, stream>>>(p);
}

// Round 8
// 159.025 us; speedup vs baseline: 5.8609x; 5.8609x over previous
//
#include <hip/hip_runtime.h>

// ---------------------------------------------------------------------------
// TransNetSweepingExplRhs — analytic reduction (derivation in R1/R2):
//   h = x@W_in^T + b_in ; th = tanh(h); r1u = h + 0.1 b1
//   Q_i = I/11 - (0.01/121) W_i^T W_i      (1-term Neumann inverse)
//   b1v = 11 th + 0.1 (r1u@W1); y1v = b1v@Q1
//   r2u = r1u - 0.1 (y1v@W1^T) + 0.1 b2
//   b2v = 10 th + y1v + 0.1 (r2u@W2); y2v = b2v@Q2
//   y2u = r2u - 0.1 (y2v@W2^T);  out = softmax(y2u@W_out^T + b_out)
// R8: R6 multi-dispatch skeleton (persistent/grid-sync was 7x slower: the
// device-scope fences invalidate L2 every stage — R7 post-mortem).
// GEMM geometry change only: block 64x128, 4 waves, wave tile 64x32
// (reads/MFMA 0.75 vs 1.0) -> 25% less LDS fragment traffic (LDS-read-bound).
// Same 3-buffer counted-vmcnt pipeline, same 8-chunk rotation swizzle,
// same K-order (bit-identical output to R6).
// ---------------------------------------------------------------------------

typedef short bf16x8 __attribute__((ext_vector_type(8)));
typedef float f32x4 __attribute__((ext_vector_type(4)));

#define M1 1048576

__device__ __forceinline__ unsigned short f2b(float f) {
  union { float f; unsigned int u; } v; v.f = f;
  unsigned int u = v.u;
  return (unsigned short)((u + 0x7FFFu + ((u >> 16) & 1u)) >> 16);
}

__device__ __forceinline__ void gload16(const void* g, void* l) {
  __builtin_amdgcn_global_load_lds(
      (const __attribute__((address_space(1))) unsigned int*)g,
      (__attribute__((address_space(3))) unsigned int*)l, 16, 0, 0);
}

// C[m,n] = sum_k A[m,k]*B[n,k], K=1024, tile 64(M)x128(N) at (bx,by), BK=64.
// 256 threads = 4 waves; wave w owns n-quarter w (wave tile 64x32, acc 4x2).
// LDS per k-tile: rows x 8 chunks of 16B, chunk c of row r at slot (c+r)&7
// (rotation swizzle, both sides: pre-swizzled global source + swizzled read).
// 3-buffer pipeline: stage t+2 while computing t; wait vmcnt(6) (t+1 stays
// in flight across the barrier) — vmcnt(0) only in the last phase.
template <int MODE>
__device__ __forceinline__ void gemm_core(
    const unsigned short* __restrict__ A, const unsigned short* __restrict__ B,
    int bx, int by,
    const float* bias0, const float* bias1,
    const float* src0, const float* src1,
    float* dstf0, float* dstf1, unsigned short* dstbf,
    short (*As)[4096], short (*Bs)[8192]) {
  const int tid = threadIdx.x;
  const int lane = tid & 63;
  const int wid = tid >> 6;  // n-quarter 0..3
  const int m0 = bx * 64;
  const int n0 = by * 128;
  const int l15 = lane & 15;
  const int kb = lane >> 4;

  // staging descriptors: A 2 chunks/thread, B 4 chunks/thread per phase
  size_t asrc[2];
  int adst[2];
  size_t bsrc[4];
  int bdst[4];
#pragma unroll
  for (int j = 0; j < 2; ++j) {
    int id = j * 256 + tid;          // 0..511 : r=id>>3 (0..63), cp=id&7
    int r = id >> 3, cp = id & 7;
    int c = (cp - r) & 7;            // global chunk stored at slot cp
    asrc[j] = (size_t)(m0 + r) * 1024 + c * 8;
    adst[j] = id * 8;
  }
#pragma unroll
  for (int j = 0; j < 4; ++j) {
    int id = j * 256 + tid;          // 0..1023 : r=id>>3 (0..127)
    int r = id >> 3, cp = id & 7;
    int c = (cp - r) & 7;
    bsrc[j] = (size_t)(n0 + r) * 1024 + c * 8;
    bdst[j] = id * 8;
  }

  f32x4 acc[4][2];
#pragma unroll
  for (int f = 0; f < 4; ++f)
#pragma unroll
    for (int g = 0; g < 2; ++g) acc[f][g] = (f32x4){0.f, 0.f, 0.f, 0.f};

#define STG(t, buf)                                                  \
  do {                                                               \
    _Pragma("unroll") for (int j = 0; j < 2; ++j)                    \
        gload16(A + asrc[j] + (t) * 64, &As[(buf)][adst[j]]);        \
    _Pragma("unroll") for (int j = 0; j < 4; ++j)                    \
        gload16(B + bsrc[j] + (t) * 64, &Bs[(buf)][bdst[j]]);        \
  } while (0)

  STG(0, 0);
  STG(1, 1);

#pragma unroll
  for (int t = 0; t < 16; ++t) {
    if (t < 15) {
      asm volatile("s_waitcnt vmcnt(6)" ::: "memory");
    } else {
      asm volatile("s_waitcnt vmcnt(0)" ::: "memory");
    }
    __builtin_amdgcn_sched_barrier(0);
    __builtin_amdgcn_s_barrier();
    __builtin_amdgcn_sched_barrier(0);
    if (t + 2 < 16) STG(t + 2, (t + 2) % 3);
    const int cb = t % 3;
#pragma unroll
    for (int ks = 0; ks < 2; ++ks) {
      bf16x8 av[4], bv[2];
#pragma unroll
      for (int f = 0; f < 4; ++f) {
        const int ra = f * 16 + l15;
        const int cp = (ks * 4 + kb + ra) & 7;
        av[f] = *reinterpret_cast<const bf16x8*>(&As[cb][ra * 64 + cp * 8]);
      }
#pragma unroll
      for (int g = 0; g < 2; ++g) {
        const int rb = wid * 32 + g * 16 + l15;
        const int cp = (ks * 4 + kb + rb) & 7;
        bv[g] = *reinterpret_cast<const bf16x8*>(&Bs[cb][rb * 64 + cp * 8]);
      }
#pragma unroll
      for (int f = 0; f < 4; ++f)
#pragma unroll
        for (int g = 0; g < 2; ++g)
          acc[f][g] = __builtin_amdgcn_mfma_f32_16x16x32_bf16(av[f], bv[g], acc[f][g], 0, 0, 0);
    }
  }
#undef STG

  // epilogue: C/D layout col = lane&15, row = (lane>>4)*4 + j
#pragma unroll
  for (int f = 0; f < 4; ++f) {
#pragma unroll
    for (int g = 0; g < 2; ++g) {
#pragma unroll
      for (int j = 0; j < 4; ++j) {
        int m = m0 + f * 16 + kb * 4 + j;
        int n = n0 + wid * 32 + g * 16 + l15;
        size_t idx = (size_t)m * 1024 + n;
        float v = acc[f][g][j];
        if (MODE == 0) {                  // raw bf16
          dstbf[idx] = f2b(v);
        } else if (MODE == 1) {           // h-stage
          float h = v + bias0[n];
          float thv = tanhf(h);
          float r = h + 0.1f * bias1[n];
          dstf0[idx] = r;
          dstf1[idx] = thv;
          dstbf[idx] = f2b(r);
        } else if (MODE == 2) {           // b1v = 11 th + 0.1 c1
          dstbf[idx] = f2b(11.0f * src0[idx] + 0.1f * v);
        } else if (MODE == 3) {           // y1v
          dstf0[idx] = v;
          dstbf[idx] = f2b(v);
        } else if (MODE == 4) {           // r2u = r1u - 0.1 d1 + 0.1 b2
          float r = src0[idx] - 0.1f * v + 0.1f * bias0[n];
          dstf0[idx] = r;
          dstbf[idx] = f2b(r);
        } else if (MODE == 5) {           // b2v = 10 th + y1v + 0.1 c2
          dstbf[idx] = f2b(10.0f * src0[idx] + src1[idx] + 0.1f * v);
        } else if (MODE == 7) {           // y2u = r2u - 0.1 d2
          dstbf[idx] = f2b(src0[idx] - 0.1f * v);
        } else if (MODE == 8) {           // logits
          dstf0[idx] = v + bias0[n];
        } else {                          // MODE 9: Q = I/11 - (0.01/121) P
          float q = (m == n ? (1.0f / 11.0f) : 0.0f) - (0.01f / 121.0f) * v;
          dstbf[idx] = f2b(q);
        }
      }
    }
  }
}

// main-chain GEMM: 256 blocks (32x8 tiles of 64x128), XCD-sharded map
template <int MODE>
__global__ __launch_bounds__(256) void k_gemm(
    const unsigned short* __restrict__ A, const unsigned short* __restrict__ B,
    const float* bias0, const float* bias1,
    const float* src0, const float* src1,
    float* dstf0, float* dstf1, unsigned short* dstbf) {
  __shared__ short As[3][4096];
  __shared__ short Bs[3][8192];
  const int b = blockIdx.x;
  const int bx = ((b & 7) << 2) | ((b >> 3) & 3);  // 0..31
  const int by = b >> 5;                           // 0..7
  gemm_core<MODE>(A, B, bx, by, bias0, bias1, src0, src1, dstf0, dstf1, dstbf, As, Bs);
}

// stage A: G0 (h-stage, blocks 0..255) + QG (Q1,Q2, blocks 256..511)
__global__ __launch_bounds__(256) void k_stageA(
    const unsigned short* __restrict__ xb, const unsigned short* __restrict__ winb,
    const unsigned short* __restrict__ wtb,
    const float* __restrict__ b_in, const float* __restrict__ b1,
    float* __restrict__ r1u, float* __restrict__ th,
    unsigned short* __restrict__ bfA0, unsigned short* __restrict__ qb) {
  __shared__ short As[3][4096];
  __shared__ short Bs[3][8192];
  const int b = blockIdx.x;
  if (b < 256) {
    const int bx = ((b & 7) << 2) | ((b >> 3) & 3);
    const int by = b >> 5;
    gemm_core<1>(xb, winb, bx, by, b_in, b1, nullptr, nullptr, r1u, th, bfA0, As, Bs);
  } else {
    int r = b - 256;
    const int z = r >> 7;
    r &= 127;
    const int qbx = ((r & 7) << 1) | ((r >> 3) & 1);  // 0..15
    const int qby = r >> 4;                           // 0..7
    const unsigned short* wt = wtb + (size_t)z * M1;
    gemm_core<9>(wt, wt, qbx, qby, nullptr, nullptr, nullptr, nullptr,
                 nullptr, nullptr, qb + (size_t)z * M1, As, Bs);
  }
}

// one-dispatch prep: W1/W2 bf16+transpose (blocks 0..2047), x (2048..4095),
// W_in (4096..5119), W_out padded (5120..6143), b_out (6144)
__global__ __launch_bounds__(256) void k_prep(
    const float* __restrict__ x, const float* __restrict__ Win,
    const float* __restrict__ W1, const float* __restrict__ W2,
    const float* __restrict__ Wout, const float* __restrict__ bout,
    unsigned short* __restrict__ xb, unsigned short* __restrict__ winb,
    unsigned short* __restrict__ wb, unsigned short* __restrict__ wtb,
    unsigned short* __restrict__ woutb, float* __restrict__ boutp) {
  __shared__ float tile[32][33];
  const int b = blockIdx.x;
  const int tid = threadIdx.x;
  if (b < 2048) {
    const float* W = (b & 1024) ? W2 : W1;
    unsigned short* Wb = wb + ((size_t)(b >> 10) << 20);
    unsigned short* WTb = wtb + ((size_t)(b >> 10) << 20);
    const int rem = b & 1023;
    const int tbx = rem & 31, tby = rem >> 5;
    const int tx = tid & 31, ty = tid >> 5;
#pragma unroll
    for (int i = ty; i < 32; i += 8) {
      float v = W[(size_t)(tby * 32 + i) * 1024 + tbx * 32 + tx];
      tile[i][tx] = v;
      Wb[(size_t)(tby * 32 + i) * 1024 + tbx * 32 + tx] = f2b(v);
    }
    __syncthreads();
#pragma unroll
    for (int i = ty; i < 32; i += 8)
      WTb[(size_t)(tbx * 32 + i) * 1024 + tby * 32 + tx] = f2b(tile[tx][i]);
  } else if (b < 4096) {
    int i = (b - 2048) * 256 + tid;
    float4 v = ((const float4*)x)[i];
    ((ushort4*)xb)[i] = (ushort4){f2b(v.x), f2b(v.y), f2b(v.z), f2b(v.w)};
  } else if (b < 5120) {
    int i = (b - 4096) * 256 + tid;
    float4 v = ((const float4*)Win)[i];
    ((ushort4*)winb)[i] = (ushort4){f2b(v.x), f2b(v.y), f2b(v.z), f2b(v.w)};
  } else if (b < 6144) {
    int i = (b - 5120) * 256 + tid;
    ushort4 o = (ushort4){0, 0, 0, 0};
    if ((i >> 8) < 1000) {
      float4 v = ((const float4*)Wout)[i];
      o = (ushort4){f2b(v.x), f2b(v.y), f2b(v.z), f2b(v.w)};
    }
    ((ushort4*)woutb)[i] = o;
  } else {
    for (int j = tid; j < 1024; j += 256) boutp[j] = (j < 1000) ? bout[j] : 0.0f;
  }
}

// row softmax over first 1000 cols of 2048x1024 logits -> 2048x1000
__global__ __launch_bounds__(256) void k_softmax(const float* __restrict__ lg,
                                                 float* __restrict__ out) {
  const int r = blockIdx.x;
  const float* p = lg + (size_t)r * 1024;
  float* q = out + (size_t)r * 1000;
  const int tid = threadIdx.x;
  const int lane = tid & 63;
  const int w = tid >> 6;
  __shared__ float redm[4];
  __shared__ float reds[4];
  float m = -3.0e38f;
  for (int i = tid; i < 1000; i += 256) m = fmaxf(m, p[i]);
#pragma unroll
  for (int o = 32; o > 0; o >>= 1) m = fmaxf(m, __shfl_xor(m, o));
  if (lane == 0) redm[w] = m;
  __syncthreads();
  m = fmaxf(fmaxf(redm[0], redm[1]), fmaxf(redm[2], redm[3]));
  float s = 0.0f;
  for (int i = tid; i < 1000; i += 256) {
    float e = __expf(p[i] - m);
    q[i] = e;
    s += e;
  }
#pragma unroll
  for (int o = 32; o > 0; o >>= 1) s += __shfl_xor(s, o);
  if (lane == 0) reds[w] = s;
  __syncthreads();
  float inv = 1.0f / (reds[0] + reds[1] + reds[2] + reds[3]);
  for (int i = tid; i < 1000; i += 256) q[i] *= inv;
}

extern "C" void kernel_launch(void* const* d_in, const int* in_sizes, int n_in,
                              void* d_out, int out_size, void* d_ws, size_t ws_size,
                              hipStream_t stream) {
  const float* x = (const float*)d_in[0];
  const float* W_in = (const float*)d_in[1];
  const float* b_in = (const float*)d_in[2];
  const float* W1 = (const float*)d_in[3];
  const float* b1 = (const float*)d_in[4];
  const float* W2 = (const float*)d_in[5];
  const float* b2 = (const float*)d_in[6];
  const float* W_out = (const float*)d_in[7];
  const float* b_out = (const float*)d_in[8];
  float* out = (float*)d_out;

  const size_t Bm = 2048, U = 1024;
  char* ws = (char*)d_ws;
  size_t off = 0;
  auto alloc = [&](size_t bytes) -> void* {
    void* p = ws + off;
    off += (bytes + 255) & ~(size_t)255;
    return p;
  };
  unsigned short* xb = (unsigned short*)alloc(Bm * U * 2);
  unsigned short* winb = (unsigned short*)alloc((size_t)M1 * 2);
  unsigned short* wb = (unsigned short*)alloc(2 * (size_t)M1 * 2);   // W1,W2
  unsigned short* wtb = (unsigned short*)alloc(2 * (size_t)M1 * 2);  // W1^T,W2^T
  unsigned short* qb = (unsigned short*)alloc(2 * (size_t)M1 * 2);   // Q1,Q2
  unsigned short* woutb = (unsigned short*)alloc((size_t)M1 * 2);
  float* boutp = (float*)alloc(U * 4);
  float* r1u = (float*)alloc(Bm * U * 4);
  float* th = (float*)alloc(Bm * U * 4);
  float* y1v = (float*)alloc(Bm * U * 4);
  float* r2u = (float*)alloc(Bm * U * 4);
  float* lgts = (float*)alloc(Bm * U * 4);
  unsigned short* bfA0 = (unsigned short*)alloc(Bm * U * 2);
  unsigned short* bfA1 = (unsigned short*)alloc(Bm * U * 2);

  k_prep<<<6145, 256, 0, stream>>>(x, W_in, W1, W2, W_out, b_out,
                                   xb, winb, wb, wtb, woutb, boutp);
  // stage A: G0 + QG
  k_stageA<<<512, 256, 0, stream>>>(xb, winb, wtb, b_in, b1, r1u, th, bfA0, qb);
  // G1: c1 = r1u@W1 -> b1v
  k_gemm<2><<<256, 256, 0, stream>>>(bfA0, wtb, nullptr, nullptr, th, nullptr,
                                     nullptr, nullptr, bfA1);
  // G2: y1v = b1v@Q1
  k_gemm<3><<<256, 256, 0, stream>>>(bfA1, qb, nullptr, nullptr, nullptr, nullptr,
                                     y1v, nullptr, bfA0);
  // G3: d1 = y1v@W1^T -> r2u
  k_gemm<4><<<256, 256, 0, stream>>>(bfA0, wb, b2, nullptr, r1u, nullptr,
                                     r2u, nullptr, bfA1);
  // G4: c2 = r2u@W2 -> b2v
  k_gemm<5><<<256, 256, 0, stream>>>(bfA1, wtb + M1, nullptr, nullptr, th, y1v,
                                     nullptr, nullptr, bfA0);
  // G5: y2v = b2v@Q2
  k_gemm<0><<<256, 256, 0, stream>>>(bfA0, qb + M1, nullptr, nullptr, nullptr, nullptr,
                                     nullptr, nullptr, bfA1);
  // G6: d2 = y2v@W2^T -> y2u
  k_gemm<7><<<256, 256, 0, stream>>>(bfA1, wb + M1, nullptr, nullptr, r2u, nullptr,
                                     nullptr, nullptr, bfA0);
  // G7: logits = y2u@Wout^T + bout
  k_gemm<8><<<256, 256, 0, stream>>>(bfA0, woutb, boutp, nullptr, nullptr, nullptr,
                                     lgts, nullptr, nullptr);

  k_softmax<<<2048, 256, 0, stream>>>(lgts, out);
}